// Round 1
// baseline (42.916 us; speedup 1.0000x reference)
//
#include <hip/hip_runtime.h>
#include <math.h>

// TrajectoryScore: B=64 candidates, N_PER=100000 obs each (contiguous segments).
// Analytic reduction: score_b depends only on {n_close, sum_m, sum_m2, sum_s2}_b.
// Single data pass, memory-bound (179.2 MB read -> ~28us roofline @ 6.3 TB/s).

#define BLOCK 256
#define BPS   25   // blocks per segment; 100000/25 = 4000 obs/block, %4 == 0

__global__ __launch_bounds__(BLOCK) void ts_main_kernel(
    const float* __restrict__ u_pred,
    const float* __restrict__ u_obs,
    const float* __restrict__ mag,
    const float* __restrict__ thresh_raw,
    float* __restrict__ acc,            // [B*4]: {cnt, sum_m, sum_m2, sum_s2}
    int n_per, float ts_min, float log_range)
{
    const int seg   = blockIdx.x / BPS;
    const int cid   = blockIdx.x % BPS;
    const int chunk = n_per / BPS;                      // 4000
    const long long base0 = (long long)seg * n_per + (long long)cid * chunk;

    const float thresh = ts_min * expf(thresh_raw[seg] * log_range);

    float cnt = 0.f, sm = 0.f, sm2 = 0.f, ss2 = 0.f;

    const int ngroups = chunk >> 2;                     // 4 obs per group
    for (int g = threadIdx.x; g < ngroups; g += BLOCK) {
        const long long base = base0 + ((long long)g << 2);
        const float4* up = reinterpret_cast<const float4*>(u_pred + base * 3);
        const float4* uo = reinterpret_cast<const float4*>(u_obs  + base * 3);
        const float4  a0 = up[0], a1 = up[1], a2 = up[2];
        const float4  b0 = uo[0], b1 = uo[1], b2 = uo[2];
        const float4  mg = *reinterpret_cast<const float4*>(mag + base);

        float dx, dy, dz, s2;

        dx = a0.x - b0.x; dy = a0.y - b0.y; dz = a0.z - b0.z;
        s2 = dx*dx + dy*dy + dz*dz;
        if (s2 < thresh) { cnt += 1.f; sm += mg.x; sm2 += mg.x*mg.x; ss2 += s2; }

        dx = a0.w - b0.w; dy = a1.x - b1.x; dz = a1.y - b1.y;
        s2 = dx*dx + dy*dy + dz*dz;
        if (s2 < thresh) { cnt += 1.f; sm += mg.y; sm2 += mg.y*mg.y; ss2 += s2; }

        dx = a1.z - b1.z; dy = a1.w - b1.w; dz = a2.x - b2.x;
        s2 = dx*dx + dy*dy + dz*dz;
        if (s2 < thresh) { cnt += 1.f; sm += mg.z; sm2 += mg.z*mg.z; ss2 += s2; }

        dx = a2.y - b2.y; dy = a2.z - b2.z; dz = a2.w - b2.w;
        s2 = dx*dx + dy*dy + dz*dz;
        if (s2 < thresh) { cnt += 1.f; sm += mg.w; sm2 += mg.w*mg.w; ss2 += s2; }
    }

    // wave (64-lane) butterfly reduce
    for (int off = 32; off > 0; off >>= 1) {
        cnt += __shfl_down(cnt, off);
        sm  += __shfl_down(sm,  off);
        sm2 += __shfl_down(sm2, off);
        ss2 += __shfl_down(ss2, off);
    }

    __shared__ float red[4][BLOCK / 64];
    const int wave = threadIdx.x >> 6;
    const int lane = threadIdx.x & 63;
    if (lane == 0) {
        red[0][wave] = cnt; red[1][wave] = sm;
        red[2][wave] = sm2; red[3][wave] = ss2;
    }
    __syncthreads();
    if (threadIdx.x == 0) {
        float t0 = 0.f, t1 = 0.f, t2 = 0.f, t3 = 0.f;
        #pragma unroll
        for (int w = 0; w < BLOCK / 64; ++w) {
            t0 += red[0][w]; t1 += red[1][w]; t2 += red[2][w]; t3 += red[3][w];
        }
        atomicAdd(&acc[seg * 4 + 0], t0);
        atomicAdd(&acc[seg * 4 + 1], t1);
        atomicAdd(&acc[seg * 4 + 2], t2);
        atomicAdd(&acc[seg * 4 + 3], t3);
    }
}

__global__ void ts_final_kernel(
    const float* __restrict__ acc,
    const float* __restrict__ R_elt,
    const float* __restrict__ thresh_raw,
    float* __restrict__ out,
    int Bn, float ts_min, float log_range)
{
    const int b = blockIdx.x * blockDim.x + threadIdx.x;
    if (b >= Bn) return;

    const float n   = acc[b * 4 + 0];
    const float sm  = acc[b * 4 + 1];
    const float sm2 = acc[b * 4 + 2];
    const float ss2 = acc[b * 4 + 3];

    float score = 0.f;
    if (n > 0.f) {
        const float thresh = ts_min * expf(thresh_raw[b] * log_range);
        const float R   = R_elt[b];
        const float lam = 0.5f * thresh / (R * R);
        // C = log(lam) - log1p(-exp(-lam)), via expm1 for small-lam accuracy
        const float C   = logf(lam) - logf(-expm1f(-lam));

        const float ssd     = sm2 - sm * (sm / n);      // n * var_raw
        const float var_raw = ssd / n;
        const float var     = fmaxf(var_raw, 1e-6f);
        const float sigma   = sqrtf(var);
        const float log_inv_root_2pi = -0.9189385332046727f;

        score = -lam * (ss2 / thresh)                 // sum of -lam*v over close
              + n * C                                 // per-obs constant of log_q_hit
              + n * (log_inv_root_2pi - logf(sigma))  // sum of log(c/sigma)
              - 0.5f * (ssd / var);                   // sum of -0.5*z^2
    }
    out[b] = score;
}

extern "C" void kernel_launch(void* const* d_in, const int* in_sizes, int n_in,
                              void* d_out, int out_size, void* d_ws, size_t ws_size,
                              hipStream_t stream) {
    const float* u_pred     = (const float*)d_in[0];
    const float* R_elt      = (const float*)d_in[1];
    const float* u_obs      = (const float*)d_in[2];
    const float* mag_obs    = (const float*)d_in[3];
    const float* thresh_raw = (const float*)d_in[4];
    // d_in[5] = seg_ids: segments are contiguous repeats -> derived, not read.

    const int B    = in_sizes[1];          // 64
    const int DATA = in_sizes[3];          // 6,400,000
    const int n_per = DATA / B;            // 100,000

    float* acc = (float*)d_ws;             // B*4 floats
    float* out = (float*)d_out;

    // constants matching the numpy float32 derivation
    const double rad_min = M_PI / 180.0 * (10.0 / 3600.0);
    const double rad_max = M_PI / 180.0 * 1.0;
    const float ts_min = (float)((2.0 * sin(rad_min / 2.0)) * (2.0 * sin(rad_min / 2.0)));
    const float ts_max = (float)((2.0 * sin(rad_max / 2.0)) * (2.0 * sin(rad_max / 2.0)));
    const float log_range = logf(ts_max / ts_min);

    hipMemsetAsync(acc, 0, (size_t)B * 4 * sizeof(float), stream);

    ts_main_kernel<<<B * BPS, BLOCK, 0, stream>>>(
        u_pred, u_obs, mag_obs, thresh_raw, acc, n_per, ts_min, log_range);

    ts_final_kernel<<<1, 64, 0, stream>>>(
        acc, R_elt, thresh_raw, out, B, ts_min, log_range);
}